// Round 3
// baseline (425.286 us; speedup 1.0000x reference)
//
#include <hip/hip_runtime.h>
#include <hip/hip_bf16.h>
#include <float.h>

#define SPLITS 16
#define MAXP   8   // max pipelined chain length (L=4 in this problem)

// ws layout:
//   packed[B]   : unsigned long long  (atomic argmax slots)
//   count[B]    : unsigned int        (split-completion counters)
//   flag[B]     : int (1 = rejected, needs argmax)
//   recrow[B]   : int
//   writecol[B] : int

__global__ void chain_kernel(
    const float* __restrict__ draft_probs,
    const float* __restrict__ target_probs,
    const float* __restrict__ uniform_probs,
    const int*   __restrict__ draft_ids,
    const int*   __restrict__ cu,
    const int*   __restrict__ bonus,
    int*         __restrict__ out,
    unsigned long long* __restrict__ packed,
    unsigned int* __restrict__ count,
    int* __restrict__ flag, int* __restrict__ recrow, int* __restrict__ writecol,
    int B, int V, int NT, int L)
{
    const int b = blockIdx.x * blockDim.x + threadIdx.x;
    if (b >= B) return;

    const int start = (b == 0) ? 0 : cu[b - 1];
    const int nd    = cu[b] - start;
    const int nchain = (nd < L) ? nd : L;

    int   did[MAXP];
    float uu[MAXP], tp[MAXP], dp[MAXP];
    const int np = (nchain < MAXP) ? nchain : MAXP;

    // Round 1: all index/uniform loads in flight together.
    #pragma unroll
    for (int i = 0; i < MAXP; ++i) {
        if (i < np) {
            did[i] = draft_ids[start + i];
            uu[i]  = uniform_probs[start + i];
        }
    }
    // Round 2: all prob gathers in flight together.
    #pragma unroll
    for (int i = 0; i < MAXP; ++i) {
        if (i < np) {
            const size_t off = (size_t)(start + i) * (size_t)V + (size_t)did[i];
            tp[i] = target_probs[off];
            dp[i] = draft_probs[off];
        }
    }

    float pi = 1.0f, U = 1.0f;
    int last = -1;
    int* row = out + (size_t)b * (L + 1);

    #pragma unroll
    for (int i = 0; i < MAXP; ++i) {
        if (i < np) {
            const bool ok = dp[i] > 0.0f;
            const float r = ok ? (tp[i] / dp[i]) : 1.0f;   // IEEE div, matches np
            pi = fminf(pi * r, 1.0f);
            U  = U * uu[i];
            if (ok && pi >= U) last = i;
        }
    }
    // general fallback for nchain > MAXP (not hit for L=4)
    for (int i = MAXP; i < nchain; ++i) {
        const int t   = start + i;
        const int d   = draft_ids[t];
        const size_t off = (size_t)t * (size_t)V + (size_t)d;
        const float tpv = target_probs[off];
        const float dpv = draft_probs[off];
        const bool ok = dpv > 0.0f;
        const float r = ok ? (tpv / dpv) : 1.0f;
        pi = fminf(pi * r, 1.0f);
        U  = U * uniform_probs[t];
        if (ok && pi >= U) last = i;
    }

    for (int i = 0; i <= L; ++i) {
        int v = -1;
        if (i <= last) v = (i < MAXP) ? did[i] : draft_ids[start + i];
        row[i] = v;
    }

    const bool rejected = (nd > 0) && (last != nd - 1);
    if (!rejected) row[nd] = bonus[b];

    int rr = start + last + 1;
    rr = rr < 0 ? 0 : (rr > NT - 1 ? NT - 1 : rr);

    flag[b]     = rejected ? 1 : 0;
    recrow[b]   = rr;
    writecol[b] = last + 1;
    packed[b]   = 0ull;
    count[b]    = 0u;
}

__global__ __launch_bounds__(256) void argmax_kernel(
    const float* __restrict__ target_probs,
    int* __restrict__ out,
    unsigned long long* __restrict__ packed,
    unsigned int* __restrict__ count,
    const int* __restrict__ flag, const int* __restrict__ recrow,
    const int* __restrict__ writecol,
    int V, int L)
{
    const int b = blockIdx.x;
    const int s = blockIdx.y;
    if (!flag[b]) return;

    const int tid = threadIdx.x;
    const float* rowbase = target_probs + (size_t)recrow[b] * (size_t)V;
    const int n4 = V >> 2;
    const int chunk4 = (n4 + SPLITS - 1) / SPLITS;
    const int lo4 = s * chunk4;
    const int hi4 = (lo4 + chunk4 < n4) ? lo4 + chunk4 : n4;

    float bestv = -FLT_MAX;
    int   besti = 0x7fffffff;
    const float4* rowp = (const float4*)rowbase;
    for (int j = lo4 + tid; j < hi4; j += 256) {
        const float4 v = rowp[j];
        const int base = j << 2;
        if (v.x > bestv) { bestv = v.x; besti = base;     }
        if (v.y > bestv) { bestv = v.y; besti = base + 1; }
        if (v.z > bestv) { bestv = v.z; besti = base + 2; }
        if (v.w > bestv) { bestv = v.w; besti = base + 3; }
    }
    if (s == SPLITS - 1) {
        for (int j = (n4 << 2) + tid; j < V; j += 256) {
            const float v = rowbase[j];
            if (v > bestv) { bestv = v; besti = j; }
        }
    }

    // wave (64-lane) shuffle reduction, first-index tie-break
    #pragma unroll
    for (int off = 32; off > 0; off >>= 1) {
        const float ov = __shfl_down(bestv, off, 64);
        const int   oi = __shfl_down(besti, off, 64);
        if (ov > bestv || (ov == bestv && oi < besti)) { bestv = ov; besti = oi; }
    }
    __shared__ float swv[4];
    __shared__ int   swi[4];
    const int wave = tid >> 6;
    if ((tid & 63) == 0) { swv[wave] = bestv; swi[wave] = besti; }
    __syncthreads();

    if (tid == 0) {
        #pragma unroll
        for (int w = 1; w < 4; ++w) {
            const float ov = swv[w];
            const int   oi = swi[w];
            if (ov > bestv || (ov == bestv && oi < besti)) { bestv = ov; besti = oi; }
        }
        const unsigned long long p =
            ((unsigned long long)__float_as_uint(bestv) << 32) |
            (unsigned long long)(0xFFFFFFFFu - (unsigned int)besti);
        atomicMax(&packed[b], p);
        __threadfence();
        const unsigned int old = atomicAdd(&count[b], 1u);
        if (old == SPLITS - 1) {
            const unsigned long long fin = atomicAdd(&packed[b], 0ull);  // coherent read
            const int idx = (int)(0xFFFFFFFFu - (unsigned int)(fin & 0xFFFFFFFFull));
            out[(size_t)b * (L + 1) + writecol[b]] = idx;
        }
    }
}

extern "C" void kernel_launch(void* const* d_in, const int* in_sizes, int n_in,
                              void* d_out, int out_size, void* d_ws, size_t ws_size,
                              hipStream_t stream) {
    const float* draft_probs   = (const float*)d_in[0];
    const float* target_probs  = (const float*)d_in[1];
    const float* uniform_probs = (const float*)d_in[2];
    const int*   draft_ids     = (const int*)d_in[3];
    const int*   cu            = (const int*)d_in[4];
    const int*   bonus         = (const int*)d_in[5];
    int*         out           = (int*)d_out;

    const int NT = in_sizes[2];
    const int V  = in_sizes[0] / NT;
    const int B  = in_sizes[4];
    const int L  = out_size / B - 1;

    char* ws = (char*)d_ws;
    unsigned long long* packed = (unsigned long long*)ws;          ws += (size_t)B * 8;
    unsigned int*       count  = (unsigned int*)ws;                ws += (size_t)B * 4;
    int*                flag   = (int*)ws;                          ws += (size_t)B * 4;
    int*                recrow = (int*)ws;                          ws += (size_t)B * 4;
    int*                writecol = (int*)ws;

    const int bthreads = 256;
    const int bblocks  = (B + bthreads - 1) / bthreads;

    chain_kernel<<<bblocks, bthreads, 0, stream>>>(
        draft_probs, target_probs, uniform_probs, draft_ids, cu, bonus,
        out, packed, count, flag, recrow, writecol, B, V, NT, L);

    dim3 grid(B, SPLITS);
    argmax_kernel<<<grid, 256, 0, stream>>>(
        target_probs, out, packed, count, flag, recrow, writecol, V, L);
}

// Round 4
// 425.126 us; speedup vs baseline: 1.0004x; 1.0004x over previous
//
#include <hip/hip_runtime.h>
#include <hip/hip_bf16.h>
#include <float.h>

#define SPLITS 16
#define MAXP   8   // max pipelined chain length (L=4 in this problem)

// ws layout:
//   packed[B]   : unsigned long long  (atomic argmax slots)
//   count[B]    : unsigned int        (split-completion counters)
//   flag[B]     : int (1 = rejected, needs argmax)
//   recrow[B]   : int
//   writecol[B] : int

__global__ void chain_kernel(
    const float* __restrict__ draft_probs,
    const float* __restrict__ target_probs,
    const float* __restrict__ uniform_probs,
    const int*   __restrict__ draft_ids,
    const int*   __restrict__ cu,
    const int*   __restrict__ bonus,
    int*         __restrict__ out,
    unsigned long long* __restrict__ packed,
    unsigned int* __restrict__ count,
    int* __restrict__ flag, int* __restrict__ recrow, int* __restrict__ writecol,
    int B, int V, int NT, int L)
{
    const int b = blockIdx.x * blockDim.x + threadIdx.x;
    if (b >= B) return;

    const int start = (b == 0) ? 0 : cu[b - 1];
    const int nd    = cu[b] - start;
    const int nchain = (nd < L) ? nd : L;

    int   did[MAXP];
    float uu[MAXP], tp[MAXP], dp[MAXP];
    const int np = (nchain < MAXP) ? nchain : MAXP;

    // Round 1: all index/uniform loads in flight together.
    #pragma unroll
    for (int i = 0; i < MAXP; ++i) {
        if (i < np) {
            did[i] = draft_ids[start + i];
            uu[i]  = uniform_probs[start + i];
        }
    }
    // Round 2: all prob gathers in flight together.
    #pragma unroll
    for (int i = 0; i < MAXP; ++i) {
        if (i < np) {
            const size_t off = (size_t)(start + i) * (size_t)V + (size_t)did[i];
            tp[i] = target_probs[off];
            dp[i] = draft_probs[off];
        }
    }

    float pi = 1.0f, U = 1.0f;
    int last = -1;

    #pragma unroll
    for (int i = 0; i < MAXP; ++i) {
        if (i < np) {
            const bool ok = dp[i] > 0.0f;
            const float r = ok ? (tp[i] / dp[i]) : 1.0f;   // IEEE div, matches np
            pi = fminf(pi * r, 1.0f);
            U  = U * uu[i];
            if (ok && pi >= U) last = i;
        }
    }
    // general fallback for nchain > MAXP (not hit for L=4)
    for (int i = MAXP; i < nchain; ++i) {
        const int t   = start + i;
        const int d   = draft_ids[t];
        const size_t off = (size_t)t * (size_t)V + (size_t)d;
        const float tpv = target_probs[off];
        const float dpv = draft_probs[off];
        const bool ok = dpv > 0.0f;
        const float r = ok ? (tpv / dpv) : 1.0f;
        pi = fminf(pi * r, 1.0f);
        U  = U * uniform_probs[t];
        if (ok && pi >= U) last = i;
    }

    int* row = out + (size_t)b * (L + 1);
    for (int i = 0; i <= L; ++i) {
        int v = -1;
        if (i <= last) v = (i < MAXP) ? did[i] : draft_ids[start + i];
        row[i] = v;
    }

    const bool rejected = (nd > 0) && (last != nd - 1);
    if (!rejected) row[nd] = bonus[b];

    int rr = start + last + 1;
    rr = rr < 0 ? 0 : (rr > NT - 1 ? NT - 1 : rr);

    flag[b]     = rejected ? 1 : 0;
    recrow[b]   = rr;
    writecol[b] = last + 1;
    packed[b]   = 0ull;
    count[b]    = 0u;
}

__global__ __launch_bounds__(256) void argmax_kernel(
    const float* __restrict__ target_probs,
    int* __restrict__ out,
    unsigned long long* __restrict__ packed,
    unsigned int* __restrict__ count,
    const int* __restrict__ flag, const int* __restrict__ recrow,
    const int* __restrict__ writecol,
    int V, int L)
{
    const int b = blockIdx.x;
    const int s = blockIdx.y;
    if (!flag[b]) return;

    const int tid = threadIdx.x;
    const float* rowbase = target_probs + (size_t)recrow[b] * (size_t)V;
    const int n4 = V >> 2;
    const int chunk4 = (n4 + SPLITS - 1) / SPLITS;
    const int lo4 = s * chunk4;
    const int hi4 = (lo4 + chunk4 < n4) ? lo4 + chunk4 : n4;

    float bestv = -FLT_MAX;
    int   besti = 0x7fffffff;
    const float4* rowp = (const float4*)rowbase;

    // 2 float4 loads in flight per iteration (512 floats/step/block)
    int j = lo4 + tid;
    for (; j + 256 < hi4; j += 512) {
        const float4 v0 = rowp[j];
        const float4 v1 = rowp[j + 256];
        const int b0 = j << 2;
        const int b1 = (j + 256) << 2;
        if (v0.x > bestv) { bestv = v0.x; besti = b0;     }
        if (v0.y > bestv) { bestv = v0.y; besti = b0 + 1; }
        if (v0.z > bestv) { bestv = v0.z; besti = b0 + 2; }
        if (v0.w > bestv) { bestv = v0.w; besti = b0 + 3; }
        if (v1.x > bestv) { bestv = v1.x; besti = b1;     }
        if (v1.y > bestv) { bestv = v1.y; besti = b1 + 1; }
        if (v1.z > bestv) { bestv = v1.z; besti = b1 + 2; }
        if (v1.w > bestv) { bestv = v1.w; besti = b1 + 3; }
    }
    for (; j < hi4; j += 256) {
        const float4 v = rowp[j];
        const int base = j << 2;
        if (v.x > bestv) { bestv = v.x; besti = base;     }
        if (v.y > bestv) { bestv = v.y; besti = base + 1; }
        if (v.z > bestv) { bestv = v.z; besti = base + 2; }
        if (v.w > bestv) { bestv = v.w; besti = base + 3; }
    }
    if (s == SPLITS - 1) {
        for (int k = (n4 << 2) + tid; k < V; k += 256) {
            const float v = rowbase[k];
            if (v > bestv) { bestv = v; besti = k; }
        }
    }

    // wave (64-lane) shuffle reduction, first-index tie-break
    #pragma unroll
    for (int off = 32; off > 0; off >>= 1) {
        const float ov = __shfl_down(bestv, off, 64);
        const int   oi = __shfl_down(besti, off, 64);
        if (ov > bestv || (ov == bestv && oi < besti)) { bestv = ov; besti = oi; }
    }
    __shared__ float swv[4];
    __shared__ int   swi[4];
    const int wave = tid >> 6;
    if ((tid & 63) == 0) { swv[wave] = bestv; swi[wave] = besti; }
    __syncthreads();

    if (tid == 0) {
        #pragma unroll
        for (int w = 1; w < 4; ++w) {
            const float ov = swv[w];
            const int   oi = swi[w];
            if (ov > bestv || (ov == bestv && oi < besti)) { bestv = ov; besti = oi; }
        }
        const unsigned long long p =
            ((unsigned long long)__float_as_uint(bestv) << 32) |
            (unsigned long long)(0xFFFFFFFFu - (unsigned int)besti);
        atomicMax(&packed[b], p);
        __threadfence();
        const unsigned int old = atomicAdd(&count[b], 1u);
        if (old == SPLITS - 1) {
            const unsigned long long fin = atomicAdd(&packed[b], 0ull);  // coherent read
            const int idx = (int)(0xFFFFFFFFu - (unsigned int)(fin & 0xFFFFFFFFull));
            out[(size_t)b * (L + 1) + writecol[b]] = idx;
        }
    }
}

extern "C" void kernel_launch(void* const* d_in, const int* in_sizes, int n_in,
                              void* d_out, int out_size, void* d_ws, size_t ws_size,
                              hipStream_t stream) {
    const float* draft_probs   = (const float*)d_in[0];
    const float* target_probs  = (const float*)d_in[1];
    const float* uniform_probs = (const float*)d_in[2];
    const int*   draft_ids     = (const int*)d_in[3];
    const int*   cu            = (const int*)d_in[4];
    const int*   bonus         = (const int*)d_in[5];
    int*         out           = (int*)d_out;

    const int NT = in_sizes[2];
    const int V  = in_sizes[0] / NT;
    const int B  = in_sizes[4];
    const int L  = out_size / B - 1;

    char* ws = (char*)d_ws;
    unsigned long long* packed = (unsigned long long*)ws;          ws += (size_t)B * 8;
    unsigned int*       count  = (unsigned int*)ws;                ws += (size_t)B * 4;
    int*                flag   = (int*)ws;                          ws += (size_t)B * 4;
    int*                recrow = (int*)ws;                          ws += (size_t)B * 4;
    int*                writecol = (int*)ws;

    const int bthreads = (B < 256) ? ((B + 63) / 64) * 64 : 256;
    const int bblocks  = (B + bthreads - 1) / bthreads;

    chain_kernel<<<bblocks, bthreads, 0, stream>>>(
        draft_probs, target_probs, uniform_probs, draft_ids, cu, bonus,
        out, packed, count, flag, recrow, writecol, B, V, NT, L);

    dim3 grid(B, SPLITS);
    argmax_kernel<<<grid, 256, 0, stream>>>(
        target_probs, out, packed, count, flag, recrow, writecol, V, L);
}